// Round 2
// baseline (233340.088 us; speedup 1.0000x reference)
//
#include <hip/hip_runtime.h>
#include <math.h>

// ---------------------------------------------------------------------------
// MIM RNN, fp32, round 1: batched 2-source conv5 with scalar (SGPR) weights,
// fused gate+conv1 kernels. B=8, NH=64, 32x32, 19 steps.
// ---------------------------------------------------------------------------

#define S 524288  // 8*64*1024 floats: one 64-ch state tensor

__device__ __forceinline__ float sigf(float x) { return 1.0f / (1.0f + expf(-x)); }

struct Job {
  const float* in1; const float* wt1;
  int s1, ci1, w1cib, w1cob, w1cout;
  const float* in2; const float* wt2;
  int s2, ci2, w2cib, w2cob, w2cout;
  float* out; int outCout, outCoBase, nCoB, blockStart;
};
struct Batch { Job j[5]; int n; };

// ---------------- batched conv5 (pad 2) -------------------------------------
// block: 256 thr = (b, y-half of 16 rows, 16-co tile). thread: 2 px x 16 co.
// weights from transposed wt[ci][k][Cout] at wave-uniform addresses (s_load).
__global__ __launch_bounds__(256) void conv5_b(Batch bt) {
  int blk = blockIdx.x;
  int ji = 0;
#pragma unroll
  for (int q = 1; q < 5; ++q)
    if (q < bt.n && blk >= bt.j[q].blockStart) ji = q;
  int local = blk - bt.j[ji].blockStart;
  int coB = local >> 4;
  int rest = local & 15;
  int b = rest >> 1, yh = rest & 1;
  int tid = threadIdx.x;
  int r0 = tid >> 5, x0 = tid & 31;

  const float* in1 = bt.j[ji].in1; const float* wt1 = bt.j[ji].wt1;
  int s1 = bt.j[ji].s1, ci1 = bt.j[ji].ci1, w1cib = bt.j[ji].w1cib,
      w1cob = bt.j[ji].w1cob, w1cout = bt.j[ji].w1cout;
  const float* in2 = bt.j[ji].in2; const float* wt2 = bt.j[ji].wt2;
  int s2 = bt.j[ji].s2, w2cib = bt.j[ji].w2cib,
      w2cob = bt.j[ji].w2cob, w2cout = bt.j[ji].w2cout;
  int totalCi = ci1 + bt.j[ji].ci2;

  __shared__ __align__(16) float s_in[4][20][40];
  for (int i = tid; i < 4 * 20 * 40; i += 256) ((float*)s_in)[i] = 0.f;
  __syncthreads();

  float acc0[16], acc1[16];
#pragma unroll
  for (int c = 0; c < 16; ++c) { acc0[c] = 0.f; acc1[c] = 0.f; }

  int ybase = yh * 16 - 2;
  for (int ci0 = 0; ci0 < totalCi; ci0 += 4) {
    // ---- stage 4 input planes (rows ybase..ybase+19, interior cols) ----
#pragma unroll
    for (int it = 0; it < 3; ++it) {
      int idx = tid + it * 256;
      if (idx < 640) {
        int ct = idx / 160, rem = idx - ct * 160;
        int lr = rem >> 3, xq = rem & 7;
        int ci = ci0 + ct;
        int gy = ybase + lr;
        if ((unsigned)gy < 32u) {
          const float* ip;
          if (ci < ci1) ip = in1 + ((size_t)b * s1 + ci) * 1024;
          else          ip = in2 + ((size_t)b * s2 + (ci - ci1)) * 1024;
          float4 v = *(const float4*)(ip + gy * 32 + xq * 4);
          *(float4*)&s_in[ct][lr][4 + xq * 4] = v;
        }
      }
    }
    __syncthreads();
    // ---- compute ----
#pragma unroll
    for (int ct = 0; ct < 4; ++ct) {
      int ci = ci0 + ct;
      const float* wbase;
      int wstride;
      if (ci < ci1) {
        wbase = wt1 + ((size_t)(w1cib + ci) * 25) * w1cout + w1cob + coB * 16;
        wstride = w1cout;
      } else {
        wbase = wt2 + ((size_t)(w2cib + ci - ci1) * 25) * w2cout + w2cob + coB * 16;
        wstride = w2cout;
      }
#pragma unroll
      for (int k = 0; k < 25; ++k) {
        const float* wr = wbase + (size_t)k * wstride;
        int dy = k / 5, dx = k - (k / 5) * 5;
        float v0 = s_in[ct][r0 + dy][2 + x0 + dx];
        float v1 = s_in[ct][r0 + 8 + dy][2 + x0 + dx];
#pragma unroll
        for (int c = 0; c < 16; ++c) {
          float w = wr[c];
          acc0[c] = fmaf(w, v0, acc0[c]);
          acc1[c] = fmaf(w, v1, acc1[c]);
        }
      }
    }
    __syncthreads();
  }
  float* op = bt.j[ji].out +
              ((size_t)b * bt.j[ji].outCout + bt.j[ji].outCoBase + coB * 16) * 1024 +
              yh * 512 + tid;
#pragma unroll
  for (int c = 0; c < 16; ++c) {
    op[(size_t)c * 1024] = acc0[c];
    op[(size_t)c * 1024 + 256] = acc1[c];
  }
}

// ---------------- weight transposes (run once per launch) -------------------
__global__ void tr5_k(const float* __restrict__ src, float* __restrict__ dst,
                      int Cin, int Cout) {
  int idx = blockIdx.x * 256 + threadIdx.x;
  if (idx >= Cout * Cin * 25) return;
  int k = idx % 25, t2 = idx / 25;
  int ci = t2 % Cin, co = t2 / Cin;
  dst[((size_t)ci * 25 + k) * Cout + co] = src[idx];
}
__global__ void tr1_k(const float* __restrict__ src, float* __restrict__ dst,
                      int Cin, int Cout) {
  int idx = blockIdx.x * 256 + threadIdx.x;
  if (idx >= Cout * Cin) return;
  int ci = idx % Cin, co = idx / Cin;
  dst[(size_t)ci * Cout + co] = src[idx];
}

// ---------------- net input build (t<10 only) -------------------------------
__global__ void build_net_k(const float* __restrict__ frames0, float* __restrict__ net,
                            int t) {
  int idx = blockIdx.x * 256 + threadIdx.x;
  int b = idx >> 14, ch = (idx >> 10) & 15, p = idx & 1023;
  int y = p >> 5, x = p & 31, py = ch >> 2, px = ch & 3;
  net[idx] = frames0[((size_t)b * 10 + t) * 16384 + (y * 4 + py) * 128 + (x * 4 + px)];
}

// ---------------- gates -----------------------------------------------------
// STH [B][256]: i,f,g,o ; STM [B][192]: i,f,g
__global__ void st_gate1_k(const float* __restrict__ sth, const float* __restrict__ stm,
                           float* __restrict__ c, float* __restrict__ m) {
  int idx = blockIdx.x * 256 + threadIdx.x;
  int b = idx >> 16, r = idx & 65535;
  const float* hb = sth + (size_t)b * 262144 + r;
  const float* mb = stm + (size_t)b * 196608 + r;
  float cn = sigf(hb[65536] + 1.f) * c[idx] + sigf(hb[0]) * tanhf(hb[131072]);
  float mn = sigf(mb[65536] + 1.f) * m[idx] + sigf(mb[0]) * tanhf(mb[131072]);
  c[idx] = cn;
  m[idx] = mn;
}

// fused: conv1(st_cl over [c0,m0]) + o-gate + h/diff write. grid 8b*4pb*4coB
__global__ __launch_bounds__(256) void st_gate2c1_k(
    const float* __restrict__ c0, const float* __restrict__ m0,
    const float* __restrict__ wcl, const float* __restrict__ sth,
    const float* __restrict__ P, float* __restrict__ h, float* __restrict__ diff) {
  int blk = blockIdx.x;
  int coB = blk & 3, pb = (blk >> 2) & 3, b = blk >> 4;
  int tid = threadIdx.x, px = pb * 256 + tid;
  float acc[16];
#pragma unroll
  for (int c = 0; c < 16; ++c) acc[c] = 0.f;
  const float* ib1 = c0 + (size_t)b * 65536 + px;
  const float* ib2 = m0 + (size_t)b * 65536 + px;
  for (int ci = 0; ci < 64; ++ci) {
    float v1 = ib1[ci * 1024], v2 = ib2[ci * 1024];
    const float* w1 = wcl + (size_t)ci * 64 + coB * 16;
    const float* w2 = wcl + (size_t)(64 + ci) * 64 + coB * 16;
#pragma unroll
    for (int c = 0; c < 16; ++c) {
      acc[c] = fmaf(w1[c], v1, acc[c]);
      acc[c] = fmaf(w2[c], v2, acc[c]);
    }
  }
#pragma unroll
  for (int c = 0; c < 16; ++c) {
    int co = coB * 16 + c;
    size_t o = (size_t)b * 65536 + (size_t)co * 1024 + px;
    float sto = sth[(size_t)b * 262144 + 196608 + (size_t)co * 1024 + px];
    float ps = P[o] + P[S + o] + P[2 * S + o] + P[3 * S + o];
    float hn = sigf(sto + ps) * tanhf(acc[c]);
    float old = h[o];
    h[o] = hn;
    diff[o] = hn - old;
  }
}

// MN [B][256]: i,g,f,o (ch+cx pre-summed)
__global__ void mimn_gate_k(const float* __restrict__ mn, float* __restrict__ dh,
                            float* __restrict__ dc, const float* __restrict__ ctw,
                            const float* __restrict__ ocw) {
  int idx = blockIdx.x * 256 + threadIdx.x;
  int b = idx >> 16, r = idx & 65535;
  const float* q = mn + (size_t)b * 262144 + r;
  float c0 = dc[idx];
  float cn = sigf(q[131072] + c0 * ctw[65536 + r] + 1.f) * c0 +
             sigf(q[0] + c0 * ctw[r]) * tanhf(q[65536]);
  float hn = sigf(q[196608] + cn * ocw[r]) * tanhf(cn);
  dc[idx] = cn;
  dh[idx] = hn;
}

// SX [B][256]: i_sx,g_sx,f_sx,o_s ; TX [B][192]: i_xt,g_xt,o_xt ; MS [B][256]: i,g,f,o
__global__ void mb_gate1_k(const float* __restrict__ sx, const float* __restrict__ tx,
                           const float* __restrict__ ms, float* __restrict__ m,
                           float* __restrict__ c, float* __restrict__ cc,
                           const float* __restrict__ ctw, const float* __restrict__ ocw) {
  int idx = blockIdx.x * 256 + threadIdx.x;
  int b = idx >> 16, r = idx & 65535;
  const float* sb = sx + (size_t)b * 262144 + r;
  const float* tb = tx + (size_t)b * 196608 + r;
  const float* qb = ms + (size_t)b * 262144 + r;
  float nm = sigf(sb[131072] + 1.f) * m[idx] + sigf(sb[0]) * tanhf(sb[65536]);
  float c0 = cc[idx];
  float mims = sigf(qb[131072] + c0 * ctw[65536 + r] + 1.f) * c0 +
               sigf(qb[0] + c0 * ctw[r]) * tanhf(qb[65536]);
  float h2 = sigf(qb[196608] + mims * ocw[r]) * tanhf(mims);
  float nc = h2 + sigf(tb[0]) * tanhf(tb[65536]);
  m[idx] = nm;
  c[idx] = nc;
  cc[idx] = mims;
}

// fused conv1(mb_last over [cI,m0]) + output gate. grid 128
__global__ __launch_bounds__(256) void mb_gate2c1_k(
    const float* __restrict__ cI, const float* __restrict__ m0,
    const float* __restrict__ wl, const float* __restrict__ sx,
    const float* __restrict__ tx, float* __restrict__ h) {
  int blk = blockIdx.x;
  int coB = blk & 3, pb = (blk >> 2) & 3, b = blk >> 4;
  int tid = threadIdx.x, px = pb * 256 + tid;
  float acc[16];
#pragma unroll
  for (int c = 0; c < 16; ++c) acc[c] = 0.f;
  const float* ib1 = cI + (size_t)b * 65536 + px;
  const float* ib2 = m0 + (size_t)b * 65536 + px;
  for (int ci = 0; ci < 64; ++ci) {
    float v1 = ib1[ci * 1024], v2 = ib2[ci * 1024];
    const float* w1 = wl + (size_t)ci * 64 + coB * 16;
    const float* w2 = wl + (size_t)(64 + ci) * 64 + coB * 16;
#pragma unroll
    for (int c = 0; c < 16; ++c) {
      acc[c] = fmaf(w1[c], v1, acc[c]);
      acc[c] = fmaf(w2[c], v2, acc[c]);
    }
  }
#pragma unroll
  for (int c = 0; c < 16; ++c) {
    int co = coB * 16 + c;
    float osum = tx[(size_t)b * 196608 + 131072 + (size_t)co * 1024 + px] +
                 sx[(size_t)b * 262144 + 196608 + (size_t)co * 1024 + px];
    h[(size_t)b * 65536 + (size_t)co * 1024 + px] = sigf(osum) * tanhf(acc[c]);
  }
}

// final conv1 w_last + unpatchify write. grid 32 = 8b*4pb
__global__ __launch_bounds__(256) void xgen_k(const float* __restrict__ h3,
                                              const float* __restrict__ wwl,
                                              float* __restrict__ xg,
                                              float* __restrict__ out, int t) {
  int blk = blockIdx.x;
  int pb = blk & 3, b = blk >> 2;
  int tid = threadIdx.x, px = pb * 256 + tid;
  float acc[16];
#pragma unroll
  for (int c = 0; c < 16; ++c) acc[c] = 0.f;
  const float* ib = h3 + (size_t)b * 65536 + px;
  for (int ci = 0; ci < 64; ++ci) {
    float v = ib[ci * 1024];
    const float* w = wwl + (size_t)ci * 16;
#pragma unroll
    for (int c = 0; c < 16; ++c) acc[c] = fmaf(w[c], v, acc[c]);
  }
  int y = px >> 5, x = px & 31;
#pragma unroll
  for (int c = 0; c < 16; ++c) {
    xg[(size_t)b * 16384 + (size_t)c * 1024 + px] = acc[c];
    if (t >= 9) {
      int py = c >> 2, pxs = c & 3;
      out[((size_t)b * 10 + (t - 9)) * 16384 + (y * 4 + py) * 128 + (x * 4 + pxs)] =
          acc[c];
    }
  }
}

// ---------------------------------------------------------------------------
extern "C" void kernel_launch(void* const* d_in, const int* in_sizes, int n_in,
                              void* d_out, int out_size, void* d_ws, size_t ws_size,
                              hipStream_t stream) {
  const float* frames0 = (const float*)d_in[0];
  const float* st_cx = (const float*)d_in[2];
  const float* st_ch = (const float*)d_in[3];
  const float* st_cm = (const float*)d_in[4];
  const float* st_co = (const float*)d_in[5];
  const float* st_cl = (const float*)d_in[6];
  const float* mb_t = (const float*)d_in[7];
  const float* mb_s = (const float*)d_in[8];
  const float* mb_x = (const float*)d_in[9];
  const float* mb_mh = (const float*)d_in[10];
  const float* mb_mx = (const float*)d_in[11];
  const float* mb_ctw = (const float*)d_in[12];
  const float* mb_ocw = (const float*)d_in[13];
  const float* mb_last = (const float*)d_in[14];
  const float* mn_ch = (const float*)d_in[15];
  const float* mn_cx = (const float*)d_in[16];
  const float* mn_ctw = (const float*)d_in[17];
  const float* mn_ocw = (const float*)d_in[18];
  const float* w_last = (const float*)d_in[19];
  float* out = (float*)d_out;

  float* ws = (float*)d_ws;
  size_t off = 0;
  auto A = [&](size_t n) { float* p = ws + off; off += n; return p; };
  float* hs[4];  for (int i = 0; i < 4; ++i) hs[i] = A(S);
  float* cs[4];  for (int i = 0; i < 4; ++i) cs[i] = A(S);
  float* memb = A(S);
  float* dh[3]; for (int i = 0; i < 3; ++i) dh[i] = A(S);
  float* dcb[3]; for (int i = 0; i < 3; ++i) dcb[i] = A(S);
  float* ccb[3]; for (int i = 0; i < 3; ++i) ccb[i] = A(S);
  float* diffb = A(S);
  size_t zeroFloats = off;  // 19*S
  float* xgen = A(131072);
  float* netb = A(131072);
  float* R1 = A(4 * S);
  float* R2 = A(3 * S);
  float* R3 = A(4 * S);
  // transposed weights
  float* wtcx = A(179200);
  float* wtch = A(409600);
  float* wtcm = A(307200);
  float* wtco = A(204800);
  float* wtmbt[3]; float* wtmbs[3]; float* wtmbx[3]; float* wtmbmh[3];
  float* wtmbmx[3]; float* wtmnch[3]; float* wtmncx[3];
  for (int li = 0; li < 3; ++li) {
    wtmbt[li] = A(307200); wtmbs[li] = A(409600); wtmbx[li] = A(409600);
    wtmbmh[li] = A(409600); wtmbmx[li] = A(409600);
    wtmnch[li] = A(409600); wtmncx[li] = A(409600);
  }
  float* wtcl = A(8192);
  float* wtmbl[3]; for (int li = 0; li < 3; ++li) wtmbl[li] = A(8192);
  float* wtwl = A(1024);
  if (ws_size < off * sizeof(float)) return;

  hipMemsetAsync(ws, 0, zeroFloats * sizeof(float), stream);

  auto tr5 = [&](const float* s, float* d, int Cin, int Cout) {
    int n = Cout * Cin * 25;
    tr5_k<<<(n + 255) / 256, 256, 0, stream>>>(s, d, Cin, Cout);
  };
  auto tr1 = [&](const float* s, float* d, int Cin, int Cout) {
    int n = Cout * Cin;
    tr1_k<<<(n + 255) / 256, 256, 0, stream>>>(s, d, Cin, Cout);
  };
  tr5(st_cx, wtcx, 16, 448);
  tr5(st_ch, wtch, 64, 256);
  tr5(st_cm, wtcm, 64, 192);
  tr5(st_co, wtco, 128, 64);
  for (int li = 0; li < 3; ++li) {
    tr5(mb_t + (size_t)li * 307200, wtmbt[li], 64, 192);
    tr5(mb_s + (size_t)li * 409600, wtmbs[li], 64, 256);
    tr5(mb_x + (size_t)li * 409600, wtmbx[li], 64, 256);
    tr5(mb_mh + (size_t)li * 409600, wtmbmh[li], 64, 256);
    tr5(mb_mx + (size_t)li * 409600, wtmbmx[li], 64, 256);
    tr5(mn_ch + (size_t)li * 409600, wtmnch[li], 64, 256);
    tr5(mn_cx + (size_t)li * 409600, wtmncx[li], 64, 256);
    tr1(mb_last + (size_t)li * 8192, wtmbl[li], 128, 64);
  }
  tr1(st_cl, wtcl, 128, 64);
  tr1(w_last, wtwl, 64, 16);

  auto mkjob = [](const float* in1, const float* wt1, int s1, int ci1, int w1cib,
                  int w1cob, int w1cout, const float* in2, const float* wt2, int s2,
                  int ci2, int w2cib, int w2cob, int w2cout, float* o, int oc, int ocb,
                  int nCoB) {
    Job j;
    j.in1 = in1; j.wt1 = wt1; j.s1 = s1; j.ci1 = ci1; j.w1cib = w1cib;
    j.w1cob = w1cob; j.w1cout = w1cout;
    j.in2 = in2; j.wt2 = wt2; j.s2 = s2; j.ci2 = ci2; j.w2cib = w2cib;
    j.w2cob = w2cob; j.w2cout = w2cout;
    j.out = o; j.outCout = oc; j.outCoBase = ocb; j.nCoB = nCoB; j.blockStart = 0;
    return j;
  };
  auto launchBatch = [&](Batch& bt) {
    int nb = 0;
    for (int q = 0; q < bt.n; ++q) { bt.j[q].blockStart = nb; nb += bt.j[q].nCoB * 16; }
    conv5_b<<<nb, 256, 0, stream>>>(bt);
  };

  for (int t = 0; t < 19; ++t) {
    const float* stIn;
    if (t < 10) {
      build_net_k<<<512, 256, 0, stream>>>(frames0, netb, t);
      stIn = netb;
    } else stIn = xgen;

    // ---- ST-LSTM convs: STH (x{i,f,g,o}+h), STM (x{i',f',g'}+m) ----
    {
      Batch bt; bt.n = 3;
      bt.j[0] = mkjob(stIn, wtcx, 16, 16, 0, 0, 448, hs[0], wtch, 64, 64, 0, 0, 256,
                      R1, 256, 0, 12);
      bt.j[1] = mkjob(stIn, wtcx, 16, 16, 0, 384, 448, hs[0], wtch, 64, 64, 0, 192, 256,
                      R1, 256, 192, 4);
      bt.j[2] = mkjob(stIn, wtcx, 16, 16, 0, 192, 448, memb, wtcm, 64, 64, 0, 0, 192,
                      R2, 192, 0, 12);
      launchBatch(bt);
    }
    st_gate1_k<<<2048, 256, 0, stream>>>(R1, R2, cs[0], memb);
    {  // st_co over [cs0,memb], 4-way ci split -> partials P0..P3 in R3
      Batch bt; bt.n = 4;
      for (int q = 0; q < 4; ++q) {
        const float* src = (q < 2) ? cs[0] : memb;
        bt.j[q] = mkjob(src + (q & 1) * 32768, wtco, 64, 32, q * 32, 0, 64,
                        nullptr, nullptr, 0, 0, 0, 0, 0, R3 + q * S, 64, 0, 4);
      }
      launchBatch(bt);
    }
    st_gate2c1_k<<<128, 256, 0, stream>>>(cs[0], memb, wtcl, R1, R3, hs[0], diffb);

    for (int i = 1; i < 4; ++i) {
      int li = i - 1;
      if (t >= 1) {
        const float* din = (i == 1) ? diffb : dh[i - 2];
        Batch bt; bt.n = 1;
        bt.j[0] = mkjob(dh[li], wtmnch[li], 64, 64, 0, 0, 256, din, wtmncx[li], 64, 64,
                        0, 0, 256, R3, 256, 0, 16);
        launchBatch(bt);
        mimn_gate_k<<<2048, 256, 0, stream>>>(R3, dh[li], dcb[li],
                                              mn_ctw + (size_t)li * 131072,
                                              mn_ocw + (size_t)li * 65536);
      }
      {
        Batch bt; bt.n = 5;
        // SX: s{i,g,f}+x{i,g,f} -> [0,192); s{o} -> [192,256)
        bt.j[0] = mkjob(memb, wtmbs[li], 64, 64, 0, 0, 256, hs[i - 1], wtmbx[li], 64,
                        64, 0, 0, 256, R1, 256, 0, 12);
        bt.j[1] = mkjob(memb, wtmbs[li], 64, 64, 0, 192, 256, nullptr, nullptr, 0, 0, 0,
                        0, 0, R1, 256, 192, 4);
        // TX: t{i,g}+x{i,g} -> [0,128); t{o}+x{o} -> [128,192)
        bt.j[2] = mkjob(hs[i], wtmbt[li], 64, 64, 0, 0, 192, hs[i - 1], wtmbx[li], 64,
                        64, 0, 0, 256, R2, 192, 0, 8);
        bt.j[3] = mkjob(hs[i], wtmbt[li], 64, 64, 0, 128, 192, hs[i - 1], wtmbx[li], 64,
                        64, 0, 192, 256, R2, 192, 128, 4);
        // MS: mh(c) + mx(diffh) all 4 chunks
        int ci2 = (t >= 1) ? 64 : 0;
        bt.j[4] = mkjob(cs[i], wtmbmh[li], 64, 64, 0, 0, 256, dh[li], wtmbmx[li], 64,
                        ci2, 0, 0, 256, R3, 256, 0, 16);
        launchBatch(bt);
      }
      mb_gate1_k<<<2048, 256, 0, stream>>>(R1, R2, R3, memb, cs[i], ccb[li],
                                           mb_ctw + (size_t)li * 131072,
                                           mb_ocw + (size_t)li * 65536);
      mb_gate2c1_k<<<128, 256, 0, stream>>>(cs[i], memb, wtmbl[li], R1, R2, hs[i]);
    }
    xgen_k<<<32, 256, 0, stream>>>(hs[3], wtwl, xgen, out, t);
  }
}

// Round 3
// 21006.706 us; speedup vs baseline: 11.1079x; 11.1079x over previous
//
#include <hip/hip_runtime.h>
#include <math.h>

// ---------------------------------------------------------------------------
// MIM RNN round 2: conv-as-GEMM on MFMA (32x32x16 bf16) with split-bf16
// (hi/lo, 3 passes) for fp32-class accuracy. B=8, NH=64, 32x32, 19 steps.
// ---------------------------------------------------------------------------

#define S 524288  // 8*64*1024

typedef __attribute__((ext_vector_type(8))) short bf16x8;
typedef __attribute__((ext_vector_type(16))) float f32x16;

__device__ __forceinline__ float sigf(float x) { return 1.0f / (1.0f + expf(-x)); }
__device__ __forceinline__ unsigned short f2bf(float f) {
  unsigned u = __float_as_uint(f);
  u += 0x7fffu + ((u >> 16) & 1u);
  return (unsigned short)(u >> 16);
}
__device__ __forceinline__ float bf2f(unsigned short h) {
  return __uint_as_float(((unsigned)h) << 16);
}

struct GJob {
  const float* x0; const float* x1;
  const unsigned short* w0; const unsigned short* w1;
  float* out;
  int cin0, cin1, taps, coutTotal, coBase;
};
struct GBatch { GJob j[8]; int n; };

// ---------------------------------------------------------------------------
// Weight prepack: W'[half][tap][ks][coB(4)][lane(64)][j(8)] bf16.
// A-frag lane layout (32x32x16): row = lane&31, k = (lane>>5)*8 + j.
__global__ void pack_k(unsigned short* dst, const float* src, int srcRow0,
                       int nRows, int dstRow0, int ciBase, int cinSrc, int taps,
                       int KS) {
  int idx = blockIdx.x * 256 + threadIdx.x;
  int total = taps * KS * 4 * 64;
  if (idx >= total) return;
  int l = idx & 63;
  int cb = (idx >> 6) & 3;
  int rest = idx >> 8;
  int ks = rest % KS, tap = rest / KS;
  int co_d = cb * 32 + (l & 31);
  if (co_d < dstRow0 || co_d >= dstRow0 + nRows) return;
  int srcRow = srcRow0 + (co_d - dstRow0);
  size_t AH = (size_t)taps * KS * 2048;
  size_t base = ((size_t)(tap * KS + ks) * 4 + cb) * 512 + (size_t)l * 8;
#pragma unroll
  for (int j = 0; j < 8; ++j) {
    int ci = ciBase + ks * 16 + (l >> 5) * 8 + j;
    float v = src[((size_t)srcRow * cinSrc + ci) * taps + tap];
    unsigned short hi = f2bf(v);
    unsigned short lo = f2bf(v - bf2f(hi));
    dst[base + j] = hi;
    dst[AH + base + j] = lo;
  }
}

// ---------------------------------------------------------------------------
// Batched implicit-GEMM conv. Block = 128co x 128px (4 rows of 32), 4 waves.
// Wave (wc,wr): 64co x 64px (2 co-tiles x 2 row-tiles). Each job = 64 blocks.
__global__ __launch_bounds__(256) void convmf_k(GBatch bt) {
  int blk = blockIdx.x;
  int ji = blk >> 6;
  int rem = blk & 63;
  int b = rem >> 3;
  int r0 = (rem & 7) * 4;
  GJob J = bt.j[ji];
  int tid = threadIdx.x;
  int l = tid & 63;
  int wv = tid >> 6;
  int wc = wv & 1, wr = wv >> 1;
  int lcol = l & 31, lg = l >> 5;

  // X LDS: [half][8 rows][36 cols x 64B], row stride 2368B (bank-offset 16).
  // (row,col) line = 32 ci bf16 in 4 slots of 16B, slot XOR-swizzled by col.
  __shared__ __align__(16) unsigned char lds[2][8][2368];

  f32x16 acc[2][2];
#pragma unroll
  for (int r = 0; r < 2; ++r)
#pragma unroll
    for (int c = 0; c < 2; ++c)
#pragma unroll
      for (int q = 0; q < 16; ++q) acc[r][c][q] = 0.f;

  for (int s = 0; s < 2; ++s) {
    const float* X = s ? J.x1 : J.x0;
    const unsigned short* W = s ? J.w1 : J.w0;
    int cin = s ? J.cin1 : J.cin0;
    if (cin == 0) continue;
    int KS = cin >> 4;
    int nst = (cin + 31) >> 5;
    for (int st = 0; st < nst; ++st) {
      int ciCnt = cin - st * 32;
      if (ciCnt > 32) ciCnt = 32;
      __syncthreads();
      {  // zero halo cols 0,1,34,35 (img cols -2,-1,32,33)
        int hh = tid & 1, sl = (tid >> 1) & 3, row = (tid >> 3) & 7, cx = tid >> 6;
        int col = cx < 2 ? cx : 32 + cx;
        float4 z = {0.f, 0.f, 0.f, 0.f};
        *(float4*)&lds[hh][row][col * 64 + sl * 16] = z;
      }
      // stage ci-pairs; lanes vary in cp (bank-clean writes)
      for (int u = tid; u < 1024; u += 256) {
        int cp = u & 15;
        int row = ((u >> 4) & 3) + ((u >> 9) << 2);
        int xq = (u >> 6) & 7;
        if (2 * cp < ciCnt) {
          int imgRow = r0 - 2 + row;
          float4 v0 = {0.f, 0.f, 0.f, 0.f}, v1 = {0.f, 0.f, 0.f, 0.f};
          if ((unsigned)imgRow < 32u) {
            const float* p0 = X + (((size_t)b * cin + st * 32 + 2 * cp) << 10) +
                              imgRow * 32 + xq * 4;
            v0 = *(const float4*)p0;
            v1 = *(const float4*)(p0 + 1024);
          }
          const float* e0 = (const float*)&v0;
          const float* e1 = (const float*)&v1;
          int slot = cp >> 2, boff = (cp & 3) * 4;
#pragma unroll
          for (int e = 0; e < 4; ++e) {
            int col = xq * 4 + 2 + e;
            int off2 = col * 64 + ((slot ^ ((col >> 1) & 3)) << 4) + boff;
            unsigned short h0 = f2bf(e0[e]);
            unsigned short h1 = f2bf(e1[e]);
            unsigned short lo0 = f2bf(e0[e] - bf2f(h0));
            unsigned short lo1 = f2bf(e1[e] - bf2f(h1));
            *(unsigned*)&lds[0][row][off2] = (unsigned)h0 | ((unsigned)h1 << 16);
            *(unsigned*)&lds[1][row][off2] = (unsigned)lo0 | ((unsigned)lo1 << 16);
          }
        }
      }
      __syncthreads();
      int kls = ciCnt >> 4;  // 2 or 1
      auto inner = [&](int dy, int dx, int tap, int bh, const unsigned short* wb) {
        const unsigned short* wt = wb + (size_t)(tap * KS + st * 2) * 2048;
        int col = lcol + dx;
        int cOff = col * 64;
        int swz = (col >> 1) & 3;
        int ro = 2 * wr + dy;
        for (int kk = 0; kk < kls; ++kk) {
          const unsigned short* wl = wt + (size_t)kk * 2048 + (wc * 2) * 512 + l * 8;
          bf16x8 a0 = *(const bf16x8*)wl;
          bf16x8 a1 = *(const bf16x8*)(wl + 512);
          int slot0 = kk * 2 + lg;
          const unsigned char* bp = &lds[bh][ro][cOff + ((slot0 ^ swz) << 4)];
          bf16x8 b0 = *(const bf16x8*)bp;
          bf16x8 b1 = *(const bf16x8*)(bp + 2368);
          acc[0][0] = __builtin_amdgcn_mfma_f32_32x32x16_bf16(a0, b0, acc[0][0], 0, 0, 0);
          acc[0][1] = __builtin_amdgcn_mfma_f32_32x32x16_bf16(a0, b1, acc[0][1], 0, 0, 0);
          acc[1][0] = __builtin_amdgcn_mfma_f32_32x32x16_bf16(a1, b0, acc[1][0], 0, 0, 0);
          acc[1][1] = __builtin_amdgcn_mfma_f32_32x32x16_bf16(a1, b1, acc[1][1], 0, 0, 0);
        }
      };
      for (int p = 0; p < 3; ++p) {
        const unsigned short* wb =
            W + (p == 1 ? (size_t)J.taps * KS * 2048 : (size_t)0);
        int bh = (p == 2) ? 1 : 0;
        if (J.taps == 25) {
          for (int dy = 0; dy < 5; ++dy)
            for (int dx = 0; dx < 5; ++dx) inner(dy, dx, dy * 5 + dx, bh, wb);
        } else {
          inner(2, 2, 0, bh, wb);
        }
      }
    }
  }
  // store: D col = lane&31 (px), row = (reg&3) + 8*(reg>>2) + 4*(lane>>5)
#pragma unroll
  for (int r = 0; r < 2; ++r) {
    int cob = J.coBase + (wc * 2 + r) * 32 + 4 * lg;
#pragma unroll
    for (int ct = 0; ct < 2; ++ct) {
      int pxrow = r0 + 2 * wr + ct;
      float* op = J.out + (((size_t)b * J.coutTotal) << 10) + pxrow * 32 + lcol;
#pragma unroll
      for (int q = 0; q < 16; ++q) {
        int co = cob + (q & 3) + 8 * (q >> 2);
        if (co < J.coutTotal) op[(size_t)co << 10] = acc[r][ct][q];
      }
    }
  }
}

// ---------------------------------------------------------------------------
__global__ void build_net_k(const float* __restrict__ frames0, float* __restrict__ net,
                            int t) {
  int idx = blockIdx.x * 256 + threadIdx.x;
  int b = idx >> 14, ch = (idx >> 10) & 15, p = idx & 1023;
  int y = p >> 5, x = p & 31, py = ch >> 2, px = ch & 3;
  net[idx] = frames0[((size_t)b * 10 + t) * 16384 + (y * 4 + py) * 128 + (x * 4 + px)];
}

__global__ void write_out_k(const float* __restrict__ xgen, float* __restrict__ out,
                            int f) {
  int idx = blockIdx.x * 256 + threadIdx.x;
  int b = idx >> 14, ch = (idx >> 10) & 15, p = idx & 1023;
  int y = p >> 5, x = p & 31, py = ch >> 2, px = ch & 3;
  out[((size_t)b * 10 + f) * 16384 + (y * 4 + py) * 128 + (x * 4 + px)] = xgen[idx];
}

// STH [b][256]: i,f,g,o ; STM [b][192]: i',f',g'
__global__ void st_gate1_k(const float* __restrict__ sth, const float* __restrict__ stm,
                           float* __restrict__ c, float* __restrict__ m) {
  int idx = blockIdx.x * 256 + threadIdx.x;
  int b = idx >> 16, r = idx & 65535;
  const float* hb = sth + (size_t)b * 262144 + r;
  const float* mb = stm + (size_t)b * 196608 + r;
  float cn = sigf(hb[65536] + 1.f) * c[idx] + sigf(hb[0]) * tanhf(hb[131072]);
  float mn = sigf(mb[65536] + 1.f) * m[idx] + sigf(mb[0]) * tanhf(mb[131072]);
  c[idx] = cn;
  m[idx] = mn;
}

__global__ void st_gate2_k(const float* __restrict__ sth, const float* __restrict__ oA,
                           const float* __restrict__ oB, const float* __restrict__ cl,
                           float* __restrict__ h, float* __restrict__ diff) {
  int idx = blockIdx.x * 256 + threadIdx.x;
  int b = idx >> 16, r = idx & 65535;
  float o = sigf(sth[(size_t)b * 262144 + 196608 + r] + oA[idx] + oB[idx]);
  float hn = o * tanhf(cl[idx]);
  float old = h[idx];
  h[idx] = hn;
  diff[idx] = hn - old;
}

// MN = a + b, chunks i,g,f,o
__global__ void mimn_gate_k(const float* __restrict__ A, const float* __restrict__ Bq,
                            float* __restrict__ dh, float* __restrict__ dc,
                            const float* __restrict__ ctw, const float* __restrict__ ocw) {
  int idx = blockIdx.x * 256 + threadIdx.x;
  int b = idx >> 16, r = idx & 65535;
  const float* a = A + (size_t)b * 262144 + r;
  const float* q = Bq + (size_t)b * 262144 + r;
  float i_ = a[0] + q[0], g_ = a[65536] + q[65536];
  float f_ = a[131072] + q[131072], o_ = a[196608] + q[196608];
  float c0 = dc[idx];
  float cn = sigf(f_ + c0 * ctw[65536 + r] + 1.f) * c0 +
             sigf(i_ + c0 * ctw[r]) * tanhf(g_);
  float hn = sigf(o_ + cn * ocw[r]) * tanhf(cn);
  dc[idx] = cn;
  dh[idx] = hn;
}

// S [256]:i,g,f,o ; T [192]:i,g,o ; X [256]:i,g,f,o ; Q=mh+mx [256]:i,g,f,o
__global__ void mb_gate1_k(const float* __restrict__ Sb, const float* __restrict__ Tb,
                           const float* __restrict__ Xb, const float* __restrict__ Qb,
                           float* __restrict__ m, float* __restrict__ c,
                           float* __restrict__ cc, const float* __restrict__ ctw,
                           const float* __restrict__ ocw) {
  int idx = blockIdx.x * 256 + threadIdx.x;
  int b = idx >> 16, r = idx & 65535;
  const float* sb = Sb + (size_t)b * 262144 + r;
  const float* tb = Tb + (size_t)b * 196608 + r;
  const float* xb = Xb + (size_t)b * 262144 + r;
  const float* qb = Qb + (size_t)b * 262144 + r;
  float i_s = sb[0], g_s = sb[65536], f_s = sb[131072];
  float i_t = tb[0], g_t = tb[65536];
  float i_x = xb[0], g_x = xb[65536], f_x = xb[131072];
  float m0 = m[idx];
  float nm = sigf(f_x + f_s + 1.f) * m0 + sigf(i_x + i_s) * tanhf(g_x + g_s);
  float q_i = qb[0], q_g = qb[65536], q_f = qb[131072], q_o = qb[196608];
  float cc0 = cc[idx];
  float mims = sigf(q_f + cc0 * ctw[65536 + r] + 1.f) * cc0 +
               sigf(q_i + cc0 * ctw[r]) * tanhf(q_g);
  float h2 = sigf(q_o + mims * ocw[r]) * tanhf(mims);
  float nc = h2 + sigf(i_x + i_t) * tanhf(g_x + g_t);
  m[idx] = nm;
  c[idx] = nc;
  cc[idx] = mims;
}

__global__ void mb_gate2_k(const float* __restrict__ Sb, const float* __restrict__ Tb,
                           const float* __restrict__ Xb, const float* __restrict__ mbl,
                           float* __restrict__ h) {
  int idx = blockIdx.x * 256 + threadIdx.x;
  int b = idx >> 16, r = idx & 65535;
  float o = sigf(Xb[(size_t)b * 262144 + 196608 + r] +
                 Tb[(size_t)b * 196608 + 131072 + r] +
                 Sb[(size_t)b * 262144 + 196608 + r]);
  h[idx] = o * tanhf(mbl[idx]);
}

// ---------------------------------------------------------------------------
extern "C" void kernel_launch(void* const* d_in, const int* in_sizes, int n_in,
                              void* d_out, int out_size, void* d_ws, size_t ws_size,
                              hipStream_t stream) {
  const float* frames0 = (const float*)d_in[0];
  const float* st_cx = (const float*)d_in[2];
  const float* st_ch = (const float*)d_in[3];
  const float* st_cm = (const float*)d_in[4];
  const float* st_co = (const float*)d_in[5];
  const float* st_cl = (const float*)d_in[6];
  const float* mb_t = (const float*)d_in[7];
  const float* mb_s = (const float*)d_in[8];
  const float* mb_x = (const float*)d_in[9];
  const float* mb_mh = (const float*)d_in[10];
  const float* mb_mx = (const float*)d_in[11];
  const float* mb_ctw = (const float*)d_in[12];
  const float* mb_ocw = (const float*)d_in[13];
  const float* mb_last = (const float*)d_in[14];
  const float* mn_ch = (const float*)d_in[15];
  const float* mn_cx = (const float*)d_in[16];
  const float* mn_ctw = (const float*)d_in[17];
  const float* mn_ocw = (const float*)d_in[18];
  const float* w_last = (const float*)d_in[19];
  float* out = (float*)d_out;

  float* ws = (float*)d_ws;
  size_t off = 0;
  auto A_ = [&](size_t n) { float* p = ws + off; off += n; return p; };
  float* hs[4]; for (int i = 0; i < 4; ++i) hs[i] = A_(S);
  float* cs[4]; for (int i = 0; i < 4; ++i) cs[i] = A_(S);
  float* memb = A_(S);
  float* dh[3]; for (int i = 0; i < 3; ++i) dh[i] = A_(S);
  float* dcb[3]; for (int i = 0; i < 3; ++i) dcb[i] = A_(S);
  float* ccb[3]; for (int i = 0; i < 3; ++i) ccb[i] = A_(S);
  float* diffb = A_(S);
  size_t zeroFloats = off;  // 19*S
  float* xgen = A_(131072);
  float* netb = A_(131072);
  float* B256a = A_(4 * S);
  float* B256b = A_(4 * S);
  float* B256c = A_(4 * S);
  float* B192 = A_(3 * S);
  float* B64a = A_(S);
  float* B64b = A_(S);
  float* B64c = A_(S);
  unsigned short* warena = (unsigned short*)(ws + off);

  // ---- W' layout ----
  size_t wOff = 0;
  auto alloc = [&](int taps, int KS) {
    size_t o = wOff;
    wOff += (size_t)2 * taps * KS * 2048;
    return o;
  };
  size_t oSTH0n = alloc(25, 1), oSTH0h = alloc(25, 4);
  size_t oSTH1n = alloc(25, 1), oSTH1h = alloc(25, 4);
  size_t oSTM0n = alloc(25, 1), oSTM0m = alloc(25, 4);
  size_t oSTM1n = alloc(25, 1), oSTM1m = alloc(25, 4);
  size_t oSTOa = alloc(25, 4), oSTOb = alloc(25, 4);
  size_t oCLa = alloc(1, 4), oCLb = alloc(1, 4);
  size_t oMNa0[3], oMNa1[3], oMNb0[3], oMNb1[3], oS0[3], oS1[3], oT0[3], oT1[3],
      oX0[3], oX1[3], oMH0[3], oMX0[3], oMH1[3], oMX1[3], oMBa[3], oMBb[3];
  for (int li = 0; li < 3; ++li) {
    oMNa0[li] = alloc(25, 4); oMNa1[li] = alloc(25, 4);
    oMNb0[li] = alloc(25, 4); oMNb1[li] = alloc(25, 4);
    oS0[li] = alloc(25, 4); oS1[li] = alloc(25, 4);
    oT0[li] = alloc(25, 4); oT1[li] = alloc(25, 4);
    oX0[li] = alloc(25, 4); oX1[li] = alloc(25, 4);
    oMH0[li] = alloc(25, 4); oMX0[li] = alloc(25, 4);
    oMH1[li] = alloc(25, 4); oMX1[li] = alloc(25, 4);
    oMBa[li] = alloc(1, 4); oMBb[li] = alloc(1, 4);
  }
  size_t oXG = alloc(1, 4);
  if (ws_size < off * sizeof(float) + wOff * sizeof(unsigned short)) return;

  hipMemsetAsync(ws, 0, zeroFloats * sizeof(float), stream);
  hipMemsetAsync(warena, 0, wOff * sizeof(unsigned short), stream);

  auto packL = [&](size_t dstOff, const float* src, int srcRow0, int nRows,
                   int dstRow0, int ciBase, int cinSrc, int taps, int KS) {
    int total = taps * KS * 4 * 64;
    pack_k<<<(total + 255) / 256, 256, 0, stream>>>(warena + dstOff, src, srcRow0,
                                                    nRows, dstRow0, ciBase, cinSrc,
                                                    taps, KS);
  };
  // ST-LSTM packs (st_cx rows: i,f,g,i',f',g',o x64)
  packL(oSTH0n, st_cx, 0, 128, 0, 0, 16, 25, 1);
  packL(oSTH0h, st_ch, 0, 128, 0, 0, 64, 25, 4);
  packL(oSTH1n, st_cx, 128, 64, 0, 0, 16, 25, 1);
  packL(oSTH1n, st_cx, 384, 64, 64, 0, 16, 25, 1);
  packL(oSTH1h, st_ch, 128, 128, 0, 0, 64, 25, 4);
  packL(oSTM0n, st_cx, 192, 128, 0, 0, 16, 25, 1);
  packL(oSTM0m, st_cm, 0, 128, 0, 0, 64, 25, 4);
  packL(oSTM1n, st_cx, 320, 64, 0, 0, 16, 25, 1);
  packL(oSTM1m, st_cm, 128, 64, 0, 0, 64, 25, 4);
  packL(oSTOa, st_co, 0, 64, 0, 0, 128, 25, 4);
  packL(oSTOb, st_co, 0, 64, 0, 64, 128, 25, 4);
  packL(oCLa, st_cl, 0, 64, 0, 0, 128, 1, 4);
  packL(oCLb, st_cl, 0, 64, 0, 64, 128, 1, 4);
  for (int li = 0; li < 3; ++li) {
    const float* ch = mn_ch + (size_t)li * 409600;
    const float* cx = mn_cx + (size_t)li * 409600;
    const float* mbs = mb_s + (size_t)li * 409600;
    const float* mbt = mb_t + (size_t)li * 307200;
    const float* mbx = mb_x + (size_t)li * 409600;
    const float* mmh = mb_mh + (size_t)li * 409600;
    const float* mmx = mb_mx + (size_t)li * 409600;
    const float* mbl = mb_last + (size_t)li * 8192;
    packL(oMNa0[li], ch, 0, 128, 0, 0, 64, 25, 4);
    packL(oMNa1[li], ch, 128, 128, 0, 0, 64, 25, 4);
    packL(oMNb0[li], cx, 0, 128, 0, 0, 64, 25, 4);
    packL(oMNb1[li], cx, 128, 128, 0, 0, 64, 25, 4);
    packL(oS0[li], mbs, 0, 128, 0, 0, 64, 25, 4);
    packL(oS1[li], mbs, 128, 128, 0, 0, 64, 25, 4);
    packL(oT0[li], mbt, 0, 128, 0, 0, 64, 25, 4);
    packL(oT1[li], mbt, 128, 64, 0, 0, 64, 25, 4);
    packL(oX0[li], mbx, 0, 128, 0, 0, 64, 25, 4);
    packL(oX1[li], mbx, 128, 128, 0, 0, 64, 25, 4);
    packL(oMH0[li], mmh, 0, 128, 0, 0, 64, 25, 4);
    packL(oMH1[li], mmh, 128, 128, 0, 0, 64, 25, 4);
    packL(oMX0[li], mmx, 0, 128, 0, 0, 64, 25, 4);
    packL(oMX1[li], mmx, 128, 128, 0, 0, 64, 25, 4);
    packL(oMBa[li], mbl, 0, 64, 0, 0, 128, 1, 4);
    packL(oMBb[li], mbl, 0, 64, 0, 64, 128, 1, 4);
  }
  packL(oXG, w_last, 0, 16, 0, 0, 64, 1, 4);

  auto mkj = [&](const float* x0, size_t w0, int cin0, const float* x1, size_t w1,
                 int cin1, int taps, float* o, int coutTotal, int coBase) {
    GJob j;
    j.x0 = x0; j.x1 = x1;
    j.w0 = warena + w0; j.w1 = warena + w1;
    j.out = o; j.cin0 = cin0; j.cin1 = cin1; j.taps = taps;
    j.coutTotal = coutTotal; j.coBase = coBase;
    return j;
  };

  for (int t = 0; t < 19; ++t) {
    const float* stIn = (t < 10) ? netb : xgen;
    if (t < 10) build_net_k<<<512, 256, 0, stream>>>(frames0, netb, t);
    {
      GBatch P; P.n = 4;
      P.j[0] = mkj(stIn, oSTH0n, 16, hs[0], oSTH0h, 64, 25, B256a, 256, 0);
      P.j[1] = mkj(stIn, oSTH1n, 16, hs[0], oSTH1h, 64, 25, B256a, 256, 128);
      P.j[2] = mkj(stIn, oSTM0n, 16, memb, oSTM0m, 64, 25, B192, 192, 0);
      P.j[3] = mkj(stIn, oSTM1n, 16, memb, oSTM1m, 64, 25, B192, 192, 128);
      convmf_k<<<256, 256, 0, stream>>>(P);
    }
    st_gate1_k<<<2048, 256, 0, stream>>>(B256a, B192, cs[0], memb);
    {
      GBatch P; P.n = 3;
      P.j[0] = mkj(cs[0], oSTOa, 64, nullptr, 0, 0, 25, B64a, 64, 0);
      P.j[1] = mkj(memb, oSTOb, 64, nullptr, 0, 0, 25, B64c, 64, 0);
      P.j[2] = mkj(cs[0], oCLa, 64, memb, oCLb, 64, 1, B64b, 64, 0);
      convmf_k<<<192, 256, 0, stream>>>(P);
    }
    st_gate2_k<<<2048, 256, 0, stream>>>(B256a, B64a, B64c, B64b, hs[0], diffb);

    for (int i = 1; i < 4; ++i) {
      int li = i - 1;
      if (t >= 1) {
        const float* din = (i == 1) ? diffb : dh[i - 2];
        GBatch P; P.n = 4;
        P.j[0] = mkj(dh[li], oMNa0[li], 64, nullptr, 0, 0, 25, B256a, 256, 0);
        P.j[1] = mkj(dh[li], oMNa1[li], 64, nullptr, 0, 0, 25, B256a, 256, 128);
        P.j[2] = mkj(din, oMNb0[li], 64, nullptr, 0, 0, 25, B256b, 256, 0);
        P.j[3] = mkj(din, oMNb1[li], 64, nullptr, 0, 0, 25, B256b, 256, 128);
        convmf_k<<<256, 256, 0, stream>>>(P);
        mimn_gate_k<<<2048, 256, 0, stream>>>(B256a, B256b, dh[li], dcb[li],
                                              mn_ctw + (size_t)li * 131072,
                                              mn_ocw + (size_t)li * 65536);
      }
      int c2 = (t >= 1) ? 64 : 0;
      {
        GBatch P; P.n = 8;
        P.j[0] = mkj(memb, oS0[li], 64, nullptr, 0, 0, 25, B256a, 256, 0);
        P.j[1] = mkj(memb, oS1[li], 64, nullptr, 0, 0, 25, B256a, 256, 128);
        P.j[2] = mkj(hs[i], oT0[li], 64, nullptr, 0, 0, 25, B192, 192, 0);
        P.j[3] = mkj(hs[i], oT1[li], 64, nullptr, 0, 0, 25, B192, 192, 128);
        P.j[4] = mkj(hs[i - 1], oX0[li], 64, nullptr, 0, 0, 25, B256b, 256, 0);
        P.j[5] = mkj(hs[i - 1], oX1[li], 64, nullptr, 0, 0, 25, B256b, 256, 128);
        P.j[6] = mkj(cs[i], oMH0[li], 64, dh[li], oMX0[li], c2, 25, B256c, 256, 0);
        P.j[7] = mkj(cs[i], oMH1[li], 64, dh[li], oMX1[li], c2, 25, B256c, 256, 128);
        convmf_k<<<512, 256, 0, stream>>>(P);
      }
      mb_gate1_k<<<2048, 256, 0, stream>>>(B256a, B192, B256b, B256c, memb, cs[i],
                                           ccb[li], mb_ctw + (size_t)li * 131072,
                                           mb_ocw + (size_t)li * 65536);
      {
        GBatch P; P.n = 1;
        P.j[0] = mkj(cs[i], oMBa[li], 64, memb, oMBb[li], 64, 1, B64a, 64, 0);
        convmf_k<<<64, 256, 0, stream>>>(P);
      }
      mb_gate2_k<<<2048, 256, 0, stream>>>(B256a, B192, B256b, B64a, hs[i]);
    }
    {
      GBatch P; P.n = 1;
      P.j[0] = mkj(hs[3], oXG, 64, nullptr, 0, 0, 1, xgen, 16, 0);
      convmf_k<<<64, 256, 0, stream>>>(P);
    }
    if (t >= 9) write_out_k<<<512, 256, 0, stream>>>(xgen, out, t - 9);
  }
}